// Round 12
// baseline (142.770 us; speedup 1.0000x reference)
//
#include <hip/hip_runtime.h>

// Scatter-add via fixed-capacity bucketing + A-folded gather4. 3 dispatches:
// zero -> place -> gather (overflow handled inside gather; empty in practice).
// Slot row layout (per node, 64 ints = 256 B): [cnt, eid0 ... eid62]
// out = A; for each edge e: out[index[e]] += B[e]
// N_NODES=100000, N_EDGES=1250000, D=64, fp32, index int32.

#define D_FEAT    64
#define ROW_INTS  64   // 1 cnt + 63 eids
#define CAP_SLOTS 63

// ---------------- fallback (round-1) path ----------------
__global__ void scatter_add_kernel(const int* __restrict__ index,
                                   const float* __restrict__ B,
                                   float* __restrict__ out,
                                   long long total) {
    long long i = (long long)blockIdx.x * blockDim.x + threadIdx.x;
    if (i >= total) return;
    int e = (int)(i >> 6);
    int f = (int)(i & 63);
    int node = index[e];
    atomicAdd(&out[(long long)node * D_FEAT + f], B[i]);
}

// ---------------- 1) zero row counts + ovf counter ----------------
__global__ void zero_kernel(int* __restrict__ rows, int* __restrict__ ovf_cnt,
                            int n_nodes) {
    int i = blockIdx.x * blockDim.x + threadIdx.x;
    if (i < n_nodes) rows[(long long)i * ROW_INTS] = 0;
    if (i == 0) *ovf_cnt = 0;
}

// ---------------- 2) place: bucket edge ids (int4 index loads) ----------------
__device__ __forceinline__ void place_one(int v, int eid,
                                          int* __restrict__ rows,
                                          int* __restrict__ ovf_cnt,
                                          int2* __restrict__ ovf,
                                          int ovf_capacity) {
    int* row = rows + (long long)v * ROW_INTS;
    int pos = atomicAdd(row, 1);          // word 0 = count
    if (pos < CAP_SLOTS) {
        row[1 + pos] = eid;               // same 256B row as the atomic
    } else {
        int op = atomicAdd(ovf_cnt, 1);
        if (op < ovf_capacity) ovf[op] = make_int2(eid, v);
    }
}

__global__ void place_kernel(const int* __restrict__ index,
                             int* __restrict__ rows,
                             int* __restrict__ ovf_cnt,
                             int2* __restrict__ ovf,
                             int ovf_capacity,
                             int n) {
    int i = (blockIdx.x * blockDim.x + threadIdx.x) * 4;
    if (i + 3 < n) {
        int4 v = *(const int4*)(index + i);
        place_one(v.x, i + 0, rows, ovf_cnt, ovf, ovf_capacity);
        place_one(v.y, i + 1, rows, ovf_cnt, ovf, ovf_capacity);
        place_one(v.z, i + 2, rows, ovf_cnt, ovf, ovf_capacity);
        place_one(v.w, i + 3, rows, ovf_cnt, ovf, ovf_capacity);
    } else {
        for (int k = i; k < n; ++k)
            place_one(index[k], k, rows, ovf_cnt, ovf, ovf_capacity);
    }
}

// ---------------- 3) gather4: out = A + sum(slot rows) ----------------
// One wave per node. One coalesced 256B row load -> lane j holds word j.
// 4 edge-groups (g = lane>>4) x 16 lanes x float4: one dwordx4 instruction
// moves 1KB/wave (4 B-rows). All __shfl are executed unconditionally by the
// full wave (convergent); loads are predicated AFTER the shfl (R6 lesson).
__global__ __launch_bounds__(256) void gather_kernel(
    const int* __restrict__ rows,
    const int* __restrict__ ovf_cnt,
    const int2* __restrict__ ovf,
    const float* __restrict__ A,
    const float* __restrict__ B,
    float* __restrict__ out, int n_nodes, int ovf_capacity)
{
    int wave = (int)((blockIdx.x * (long long)blockDim.x + threadIdx.x) >> 6);
    int lane = threadIdx.x & 63;
    if (wave >= n_nodes) return;
    int g   = lane >> 4;
    int sub = lane & 15;

    // lane j holds rows[wave*64 + j]
    int rowval = rows[(long long)wave * ROW_INTS + lane];
    int c = __shfl(rowval, 0, 64);        // count (wave-uniform)
    if (c > CAP_SLOTS) c = CAP_SLOTS;

    float4 acc = make_float4(0.f, 0.f, 0.f, 0.f);

    int j = 0;
    // 8 edges in flight: 2 x (4 groups x dwordx4)
    for (; j + 7 < c; j += 8) {
        int ea = __shfl(rowval, 1 + j + g, 64);
        int eb = __shfl(rowval, 5 + j + g, 64);
        float4 ba = *((const float4*)(B + (long long)ea * D_FEAT) + sub);
        float4 bb = *((const float4*)(B + (long long)eb * D_FEAT) + sub);
        acc.x += ba.x; acc.y += ba.y; acc.z += ba.z; acc.w += ba.w;
        acc.x += bb.x; acc.y += bb.y; acc.z += bb.z; acc.w += bb.w;
    }
    for (; j + 3 < c; j += 4) {
        int ea = __shfl(rowval, 1 + j + g, 64);
        float4 ba = *((const float4*)(B + (long long)ea * D_FEAT) + sub);
        acc.x += ba.x; acc.y += ba.y; acc.z += ba.z; acc.w += ba.w;
    }
    // remainder rem in 0..3: shfl convergent, load predicated
    {
        int rem = c - j;
        int src = 1 + j + g; if (src > 63) src = 63;
        int er = __shfl(rowval, src, 64);
        if (g < rem) {
            float4 br = *((const float4*)(B + (long long)er * D_FEAT) + sub);
            acc.x += br.x; acc.y += br.y; acc.z += br.z; acc.w += br.w;
        }
    }

    // reduce across the 4 edge-groups (lane bits 4,5)
    acc.x += __shfl_xor(acc.x, 16); acc.y += __shfl_xor(acc.y, 16);
    acc.z += __shfl_xor(acc.z, 16); acc.w += __shfl_xor(acc.w, 16);
    acc.x += __shfl_xor(acc.x, 32); acc.y += __shfl_xor(acc.y, 32);
    acc.z += __shfl_xor(acc.z, 32); acc.w += __shfl_xor(acc.w, 32);

    // overflow contributions (ovf_cnt == 0 in practice: one cached load)
    int novf = *ovf_cnt;
    if (novf > ovf_capacity) novf = ovf_capacity;
    for (int i = 0; i < novf; ++i) {
        int2 p = ovf[i];
        if (p.y == wave && g == 0) {
            float4 br = *((const float4*)(B + (long long)p.x * D_FEAT) + sub);
            acc.x += br.x; acc.y += br.y; acc.z += br.z; acc.w += br.w;
        }
    }

    if (g == 0) {
        float4 a = *((const float4*)(A + (long long)wave * D_FEAT) + sub);
        *((float4*)(out + (long long)wave * D_FEAT) + sub) =
            make_float4(a.x + acc.x, a.y + acc.y, a.z + acc.z, a.w + acc.w);
    }
}

extern "C" void kernel_launch(void* const* d_in, const int* in_sizes, int n_in,
                              void* d_out, int out_size, void* d_ws, size_t ws_size,
                              hipStream_t stream) {
    const int*   index = (const int*)d_in[0];   // (N_EDGES,) int32
    const float* A     = (const float*)d_in[1]; // (N_NODES, 64) f32
    const float* B     = (const float*)d_in[2]; // (N_EDGES, 64) f32
    float*       out   = (float*)d_out;         // (N_NODES, 64) f32

    const int n_edges = in_sizes[0];
    const int n_nodes = out_size / D_FEAT;

    size_t need = (2                              // ovf_cnt + pad
                   + (size_t)n_edges * 2          // ovf pairs
                   + (size_t)n_nodes * ROW_INTS   // slot rows
                   + 64                           // alignment slack
                  ) * sizeof(int);

    if (ws_size < need) {
        hipMemcpyAsync(out, A, (size_t)out_size * sizeof(float),
                       hipMemcpyDeviceToDevice, stream);
        long long total = (long long)n_edges * D_FEAT;
        int block = 256;
        long long grid = (total + block - 1) / block;
        scatter_add_kernel<<<(int)grid, block, 0, stream>>>(index, B, out, total);
        return;
    }

    int*  ovf_cnt = (int*)d_ws;                       // 1 (+1 pad)
    int2* ovf     = (int2*)(ovf_cnt + 2);             // n_edges pairs
    int*  rows    = (int*)(ovf + n_edges);            // n_nodes * ROW_INTS
    rows = (int*)(((uintptr_t)rows + 255) & ~(uintptr_t)255);  // 256B-align

    const int block = 256;

    // 1) zero row counts + ovf counter
    zero_kernel<<<(n_nodes + block - 1) / block, block, 0, stream>>>(
        rows, ovf_cnt, n_nodes);
    // 2) place edges into per-node slot rows
    {
        int nthreads = (n_edges + 3) / 4;
        place_kernel<<<(nthreads + block - 1) / block, block, 0, stream>>>(
            index, rows, ovf_cnt, ovf, n_edges, n_edges);
    }
    // 3) gather4: out = A + sum of bucketed B rows (+ overflow, empty)
    {
        long long threads = (long long)n_nodes * 64;
        int grid = (int)((threads + block - 1) / block);
        gather_kernel<<<grid, block, 0, stream>>>(
            rows, ovf_cnt, ovf, A, B, out, n_nodes, n_edges);
    }
}

// Round 13
// 141.359 us; speedup vs baseline: 1.0100x; 1.0100x over previous
//
#include <hip/hip_runtime.h>

// Scatter-add via fixed-capacity bucketing + A-folded gather4. 3 dispatches:
// zero -> place -> gather (overflow handled inside gather; ~empty in practice).
// Slot row layout (per node, 32 ints = 128 B): [cnt, eid0 ... eid30]
// out = A; for each edge e: out[index[e]] += B[e]
// N_NODES=100000, N_EDGES=1250000, D=64, fp32, index int32.
// Degree ~ Poisson(12.5): P(deg>31) ~ 3e-6/node -> overflow list holds ~0-3
// entries; gather's ovf scan keeps any-input correctness.

#define D_FEAT    64
#define ROW_INTS  32   // 1 cnt + 31 eids = 128 B
#define CAP_SLOTS 31

// ---------------- fallback (round-1) path ----------------
__global__ void scatter_add_kernel(const int* __restrict__ index,
                                   const float* __restrict__ B,
                                   float* __restrict__ out,
                                   long long total) {
    long long i = (long long)blockIdx.x * blockDim.x + threadIdx.x;
    if (i >= total) return;
    int e = (int)(i >> 6);
    int f = (int)(i & 63);
    int node = index[e];
    atomicAdd(&out[(long long)node * D_FEAT + f], B[i]);
}

// ---------------- 1) zero row counts + ovf counter ----------------
__global__ void zero_kernel(int* __restrict__ rows, int* __restrict__ ovf_cnt,
                            int n_nodes) {
    int i = blockIdx.x * blockDim.x + threadIdx.x;
    if (i < n_nodes) rows[(long long)i * ROW_INTS] = 0;
    if (i == 0) *ovf_cnt = 0;
}

// ---------------- 2) place: bucket edge ids (int4 index loads) ----------------
__device__ __forceinline__ void place_one(int v, int eid,
                                          int* __restrict__ rows,
                                          int* __restrict__ ovf_cnt,
                                          int2* __restrict__ ovf,
                                          int ovf_capacity) {
    int* row = rows + (long long)v * ROW_INTS;
    int pos = atomicAdd(row, 1);          // word 0 = count
    if (pos < CAP_SLOTS) {
        row[1 + pos] = eid;               // same 128B row as the atomic
    } else {
        int op = atomicAdd(ovf_cnt, 1);
        if (op < ovf_capacity) ovf[op] = make_int2(eid, v);
    }
}

__global__ void place_kernel(const int* __restrict__ index,
                             int* __restrict__ rows,
                             int* __restrict__ ovf_cnt,
                             int2* __restrict__ ovf,
                             int ovf_capacity,
                             int n) {
    int i = (blockIdx.x * blockDim.x + threadIdx.x) * 4;
    if (i + 3 < n) {
        int4 v = *(const int4*)(index + i);
        place_one(v.x, i + 0, rows, ovf_cnt, ovf, ovf_capacity);
        place_one(v.y, i + 1, rows, ovf_cnt, ovf, ovf_capacity);
        place_one(v.z, i + 2, rows, ovf_cnt, ovf, ovf_capacity);
        place_one(v.w, i + 3, rows, ovf_cnt, ovf, ovf_capacity);
    } else {
        for (int k = i; k < n; ++k)
            place_one(index[k], k, rows, ovf_cnt, ovf, ovf_capacity);
    }
}

// ---------------- 3) gather4: out = A + sum(slot rows) ----------------
// One wave per node. Lanes 0-31 load the 128B row (lane j holds word j);
// every __shfl is executed unconditionally by the full wave with source
// lane <= 31 (clamped for unused lanes); loads predicated AFTER the shfl.
// 4 edge-groups (g = lane>>4) x 16 lanes x float4 -> 1KB/wave per step.
__global__ __launch_bounds__(256) void gather_kernel(
    const int* __restrict__ rows,
    const int* __restrict__ ovf_cnt,
    const int2* __restrict__ ovf,
    const float* __restrict__ A,
    const float* __restrict__ B,
    float* __restrict__ out, int n_nodes, int ovf_capacity)
{
    int wave = (int)((blockIdx.x * (long long)blockDim.x + threadIdx.x) >> 6);
    int lane = threadIdx.x & 63;
    if (wave >= n_nodes) return;
    int g   = lane >> 4;
    int sub = lane & 15;

    // lanes 0..31: lane j holds rows[wave*32 + j]
    int rowval = 0;
    if (lane < ROW_INTS)
        rowval = rows[(long long)wave * ROW_INTS + lane];
    int c = __shfl(rowval, 0, 64);        // count (wave-uniform)
    if (c > CAP_SLOTS) c = CAP_SLOTS;

    float4 acc = make_float4(0.f, 0.f, 0.f, 0.f);

    int j = 0;
    // 8 edges in flight: 2 x (4 groups x dwordx4)   (srcs <= c <= 31)
    for (; j + 7 < c; j += 8) {
        int ea = __shfl(rowval, 1 + j + g, 64);
        int eb = __shfl(rowval, 5 + j + g, 64);
        float4 ba = *((const float4*)(B + (long long)ea * D_FEAT) + sub);
        float4 bb = *((const float4*)(B + (long long)eb * D_FEAT) + sub);
        acc.x += ba.x; acc.y += ba.y; acc.z += ba.z; acc.w += ba.w;
        acc.x += bb.x; acc.y += bb.y; acc.z += bb.z; acc.w += bb.w;
    }
    for (; j + 3 < c; j += 4) {
        int ea = __shfl(rowval, 1 + j + g, 64);
        float4 ba = *((const float4*)(B + (long long)ea * D_FEAT) + sub);
        acc.x += ba.x; acc.y += ba.y; acc.z += ba.z; acc.w += ba.w;
    }
    // remainder rem in 0..3: shfl convergent (src clamped to 31), load predicated
    {
        int rem = c - j;
        int src = 1 + j + g; if (src > 31) src = 31;
        int er = __shfl(rowval, src, 64);
        if (g < rem) {
            float4 br = *((const float4*)(B + (long long)er * D_FEAT) + sub);
            acc.x += br.x; acc.y += br.y; acc.z += br.z; acc.w += br.w;
        }
    }

    // reduce across the 4 edge-groups (lane bits 4,5)
    acc.x += __shfl_xor(acc.x, 16); acc.y += __shfl_xor(acc.y, 16);
    acc.z += __shfl_xor(acc.z, 16); acc.w += __shfl_xor(acc.w, 16);
    acc.x += __shfl_xor(acc.x, 32); acc.y += __shfl_xor(acc.y, 32);
    acc.z += __shfl_xor(acc.z, 32); acc.w += __shfl_xor(acc.w, 32);

    // overflow contributions (ovf_cnt ~= 0: one cached word per wave)
    int novf = *ovf_cnt;
    if (novf > ovf_capacity) novf = ovf_capacity;
    for (int i = 0; i < novf; ++i) {
        int2 p = ovf[i];
        if (p.y == wave && g == 0) {
            float4 br = *((const float4*)(B + (long long)p.x * D_FEAT) + sub);
            acc.x += br.x; acc.y += br.y; acc.z += br.z; acc.w += br.w;
        }
    }

    if (g == 0) {
        float4 a = *((const float4*)(A + (long long)wave * D_FEAT) + sub);
        *((float4*)(out + (long long)wave * D_FEAT) + sub) =
            make_float4(a.x + acc.x, a.y + acc.y, a.z + acc.z, a.w + acc.w);
    }
}

extern "C" void kernel_launch(void* const* d_in, const int* in_sizes, int n_in,
                              void* d_out, int out_size, void* d_ws, size_t ws_size,
                              hipStream_t stream) {
    const int*   index = (const int*)d_in[0];   // (N_EDGES,) int32
    const float* A     = (const float*)d_in[1]; // (N_NODES, 64) f32
    const float* B     = (const float*)d_in[2]; // (N_EDGES, 64) f32
    float*       out   = (float*)d_out;         // (N_NODES, 64) f32

    const int n_edges = in_sizes[0];
    const int n_nodes = out_size / D_FEAT;

    size_t need = (2                              // ovf_cnt + pad
                   + (size_t)n_edges * 2          // ovf pairs
                   + (size_t)n_nodes * ROW_INTS   // slot rows
                   + 64                           // alignment slack
                  ) * sizeof(int);

    if (ws_size < need) {
        hipMemcpyAsync(out, A, (size_t)out_size * sizeof(float),
                       hipMemcpyDeviceToDevice, stream);
        long long total = (long long)n_edges * D_FEAT;
        int block = 256;
        long long grid = (total + block - 1) / block;
        scatter_add_kernel<<<(int)grid, block, 0, stream>>>(index, B, out, total);
        return;
    }

    int*  ovf_cnt = (int*)d_ws;                       // 1 (+1 pad)
    int2* ovf     = (int2*)(ovf_cnt + 2);             // n_edges pairs
    int*  rows    = (int*)(ovf + n_edges);            // n_nodes * ROW_INTS
    rows = (int*)(((uintptr_t)rows + 127) & ~(uintptr_t)127);  // 128B-align

    const int block = 256;

    // 1) zero row counts + ovf counter
    zero_kernel<<<(n_nodes + block - 1) / block, block, 0, stream>>>(
        rows, ovf_cnt, n_nodes);
    // 2) place edges into per-node slot rows
    {
        int nthreads = (n_edges + 3) / 4;
        place_kernel<<<(nthreads + block - 1) / block, block, 0, stream>>>(
            index, rows, ovf_cnt, ovf, n_edges, n_edges);
    }
    // 3) gather4: out = A + sum of bucketed B rows (+ overflow, ~empty)
    {
        long long threads = (long long)n_nodes * 64;
        int grid = (int)((threads + block - 1) / block);
        gather_kernel<<<grid, block, 0, stream>>>(
            rows, ovf_cnt, ovf, A, B, out, n_nodes, n_edges);
    }
}